// Round 9
// baseline (415.893 us; speedup 1.0000x reference)
//
#include <hip/hip_runtime.h>
#include <stdint.h>

typedef __attribute__((ext_vector_type(8))) short short8;
typedef __attribute__((ext_vector_type(4))) short short4v;
typedef __attribute__((ext_vector_type(4))) float float4v;

__device__ __forceinline__ float bf2f(unsigned short s) {
    union { unsigned int u; float f; } c; c.u = ((unsigned int)s) << 16; return c.f;
}
__device__ __forceinline__ unsigned short f2bf(float f) {
    union { float f; unsigned int u; } c; c.f = f;
    unsigned int x = c.u;
    unsigned int r = x + 0x7fffu + ((x >> 16) & 1u);   // RNE
    return (unsigned short)(r >> 16);
}
__device__ __forceinline__ void unpack2(unsigned int u, float& lo, float& hi) {
    union { unsigned int uu; float ff; } a, b;
    a.uu = u << 16;          // low bf16
    b.uu = u & 0xffff0000u;  // high bf16
    lo = a.ff; hi = b.ff;
}

// ================= CSR build via bucket sort (bucket = dst>>8) =================
__global__ __launch_bounds__(256) void bs_count(const int* __restrict__ dst, int nE,
                                                int* __restrict__ bucketCnt) {
    __shared__ int c[512];
    int t = threadIdx.x;
    for (int i = t; i < 512; i += 256) c[i] = 0;
    __syncthreads();
    int base = blockIdx.x * 4096;
    for (int i = t; i < 4096; i += 256) {
        int e = base + i;
        if (e < nE) atomicAdd(&c[dst[e] >> 8], 1);
    }
    __syncthreads();
    for (int i = t; i < 512; i += 256)
        if (c[i]) atomicAdd(&bucketCnt[i], c[i]);
}

__global__ __launch_bounds__(512) void bs_scan(const int* __restrict__ bucketCnt,
                                               int* __restrict__ bucketBase,
                                               int* __restrict__ bucketCur,
                                               int* __restrict__ off, int M, int nE) {
    __shared__ int s[512];
    int t = threadIdx.x;
    int v = bucketCnt[t];
    s[t] = v;
    __syncthreads();
    for (int o = 1; o < 512; o <<= 1) {
        int x = (t >= o) ? s[t - o] : 0;
        __syncthreads();
        s[t] += x;
        __syncthreads();
    }
    bucketBase[t] = s[t] - v;
    bucketCur[t] = s[t] - v;
    if (t == 511) bucketBase[512] = s[511];
    if (t == 0) off[M] = nE;
}

// packed entry: src (bits 0..16) | (dst&255)<<17
__global__ __launch_bounds__(512) void bs_scatter(const int* __restrict__ src,
                                                  const int* __restrict__ dst, int nE,
                                                  int* __restrict__ bucketCur,
                                                  unsigned int* __restrict__ ebuf) {
    __shared__ int cnt[512];
    __shared__ int excl[512];
    __shared__ int chunk[512];
    __shared__ unsigned int buf[4096];
    __shared__ unsigned short bkt[4096];
    int t = threadIdx.x;
    cnt[t] = 0;
    __syncthreads();
    int base = blockIdx.x * 4096;
    int n = nE - base; if (n > 4096) n = 4096;
    unsigned int pk[8]; int bk[8]; int rk[8];
#pragma unroll
    for (int u = 0; u < 8; ++u) {
        int i = t + u * 512;
        if (i < n) {
            int e = base + i;
            int d = dst[e];
            int b = d >> 8;
            bk[u] = b;
            pk[u] = (unsigned int)src[e] | ((unsigned int)(d & 255) << 17);
            rk[u] = atomicAdd(&cnt[b], 1);
        } else bk[u] = -1;
    }
    __syncthreads();
    excl[t] = cnt[t];
    __syncthreads();
    for (int o = 1; o < 512; o <<= 1) {
        int x = (t >= o) ? excl[t - o] : 0;
        __syncthreads();
        excl[t] += x;
        __syncthreads();
    }
    int ex = excl[t] - cnt[t];
    __syncthreads();
    excl[t] = ex;
    if (cnt[t]) chunk[t] = atomicAdd(&bucketCur[t], cnt[t]);
    __syncthreads();
#pragma unroll
    for (int u = 0; u < 8; ++u) {
        if (bk[u] >= 0) {
            int lp = excl[bk[u]] + rk[u];
            buf[lp] = pk[u];
            bkt[lp] = (unsigned short)bk[u];
        }
    }
    __syncthreads();
    for (int i = t; i < n; i += 512) {
        int b = bkt[i];
        ebuf[chunk[b] + (i - excl[b])] = buf[i];
    }
}

__global__ __launch_bounds__(512) void bs_build(const unsigned int* __restrict__ ebuf,
                                                const int* __restrict__ bucketBase,
                                                int* __restrict__ off,
                                                int* __restrict__ esrc, int M) {
    __shared__ int cnt[256];
    __shared__ int excl[256];
    __shared__ int obuf[5120];
    int t = threadIdx.x, b = blockIdx.x;
    int base = bucketBase[b];
    int n = bucketBase[b + 1] - base;
    if (t < 256) cnt[t] = 0;
    __syncthreads();
    unsigned int pk[10]; int dl[10]; int rk[10];
#pragma unroll
    for (int u = 0; u < 10; ++u) {
        int i = t + u * 512;
        if (i < n) {
            unsigned int p = ebuf[base + i];
            pk[u] = p;
            int d = (p >> 17) & 255;
            dl[u] = d;
            rk[u] = atomicAdd(&cnt[d], 1);
        } else dl[u] = -1;
    }
    __syncthreads();
    if (t < 256) excl[t] = cnt[t];
    __syncthreads();
    for (int o = 1; o < 256; o <<= 1) {
        int x = (t < 256 && t >= o) ? excl[t - o] : 0;
        __syncthreads();
        if (t < 256) excl[t] += x;
        __syncthreads();
    }
    if (t < 256) {
        int ex = excl[t] - cnt[t];
        int node = b * 256 + t;
        if (node < M) off[node] = base + ex;
        excl[t] = ex;
    }
    __syncthreads();
#pragma unroll
    for (int u = 0; u < 10; ++u) {
        if (dl[u] >= 0) {
            int lp = excl[dl[u]] + rk[u];
            if (lp < 5120) obuf[lp] = (int)(pk[u] & 0x1FFFF);
        }
    }
    __syncthreads();
    for (int i = t; i < n; i += 512) esrc[base + i] = obuf[i];
}

// ==== combined prep: zero bucketCnt; weights fp32 W[k][n] -> bf16 [n][k]; x -> bf16 ====
struct Prep {
    const float* W[6];
    unsigned short* hi[6];
    const float4* xin;
    uint2* xout;
    int n4;
    int* bucketCnt;
};

__global__ __launch_bounds__(256) void k_prep(Prep p) {
    int b = blockIdx.x;
    if (b == 0) {             // zero bucketCnt (runs before bs_count dispatch)
        p.bucketCnt[threadIdx.x] = 0;
        p.bucketCnt[threadIdx.x + 256] = 0;
    }
    if (b < 344) {
        int mat = b >> 6;     // mats 0..4: 64 blocks each; mat 5: blocks 320..343
        int rel = b - mat * 64;
        int NPAD = (mat == 5) ? 48 : 128;
        int N = (mat == 5) ? 40 : 128;
        int idx = rel * 256 + threadIdx.x;
        if (idx >= NPAD * 128) return;
        int n = idx >> 7, k = idx & 127;
        float w = (n < N) ? p.W[mat][k * N + n] : 0.f;
        p.hi[mat][idx] = f2bf(w);
    } else {
        int i = (b - 344) * 256 + threadIdx.x;
        if (i >= p.n4) return;
        float4 v = p.xin[i];
        uint2 o;
        o.x = ((unsigned int)f2bf(v.y) << 16) | f2bf(v.x);
        o.y = ((unsigned int)f2bf(v.w) << 16) | f2bf(v.z);
        p.xout[i] = o;
    }
}

// ======= aggregation: a = (1+eps)*h + sum_{j->i} h_j (h bf16) ; emit bf16 =======
__device__ __forceinline__ void acc8(uint4 v, float* s) {
    float a, b;
    unpack2(v.x, a, b); s[0] += a; s[1] += b;
    unpack2(v.y, a, b); s[2] += a; s[3] += b;
    unpack2(v.z, a, b); s[4] += a; s[5] += b;
    unpack2(v.w, a, b); s[6] += a; s[7] += b;
}

__global__ __launch_bounds__(256) void k_aggr(const uint4* __restrict__ Hin,
                                              const int* __restrict__ off,
                                              const int* __restrict__ esrc,
                                              const float* __restrict__ epsp,
                                              uint4* __restrict__ Ahi,
                                              int base, int limit) {
    int w = threadIdx.x >> 6, lane = threadIdx.x & 63;
    int li = lane & 15, q = lane >> 4;
    int node = base + blockIdx.x * 16 + w * 4 + q;
    if (node >= limit) return;
    float ep = 1.0f + epsp[0];
    uint4 ow = Hin[node * 16 + li];
    float s[8] = {0.f, 0.f, 0.f, 0.f, 0.f, 0.f, 0.f, 0.f};
    int i = off[node], e = off[node + 1];
    for (; i + 8 <= e; i += 8) {
        uint4 v[8];
#pragma unroll
        for (int j = 0; j < 8; ++j) v[j] = Hin[esrc[i + j] * 16 + li];
#pragma unroll
        for (int j = 0; j < 8; ++j) acc8(v[j], s);
    }
    if (i < e) {
        int last = e - 1;
        uint4 v[8];
#pragma unroll
        for (int j = 0; j < 8; ++j) {
            int idx = i + j;
            int cl = idx < last ? idx : last;
            v[j] = Hin[esrc[cl] * 16 + li];
        }
#pragma unroll
        for (int j = 0; j < 8; ++j) {
            bool ok = (i + j) < e;
            uint4 u;
            u.x = ok ? v[j].x : 0u;
            u.y = ok ? v[j].y : 0u;
            u.z = ok ? v[j].z : 0u;
            u.w = ok ? v[j].w : 0u;
            acc8(u, s);
        }
    }
    float o[8];
    unpack2(ow.x, o[0], o[1]);
    unpack2(ow.y, o[2], o[3]);
    unpack2(ow.z, o[4], o[5]);
    unpack2(ow.w, o[6], o[7]);
#pragma unroll
    for (int k = 0; k < 8; ++k) s[k] = ep * o[k] + s[k];
    uint4 r;
    r.x = ((unsigned int)f2bf(s[1]) << 16) | f2bf(s[0]);
    r.y = ((unsigned int)f2bf(s[3]) << 16) | f2bf(s[2]);
    r.z = ((unsigned int)f2bf(s[5]) << 16) | f2bf(s[4]);
    r.w = ((unsigned int)f2bf(s[7]) << 16) | f2bf(s[6]);
    Ahi[node * 16 + li] = r;
}

// ============ fused 2-layer MLP, transpose-free, fully software-pipelined ============
// All global loads (Ahi frags, W1 staging words, W2 staging words) issued at kernel
// top so no global latency sits inside the barrier-fenced sections.
// launch_bounds(256,2): LDS (34 KB) caps blocks/CU at 4; don't VGPR-throttle (the
// round-5..8 (256,3/4) bound is suspected to have forced scratch spills).
template <int NT2, bool LOGITS>
__global__ __launch_bounds__(256, 2) void k_mlp(const unsigned short* __restrict__ AhiS,
                                                const unsigned short* __restrict__ W1h,
                                                const float* __restrict__ B1,
                                                const unsigned short* __restrict__ W2h,
                                                const float* __restrict__ B2,
                                                unsigned short* __restrict__ HOut,
                                                float* __restrict__ LOut, int M) {
    __shared__ short wbuf[128 * 136];     // 272 B row stride
    int t = threadIdx.x, w = t >> 6, lane = t & 63;
    int lm = lane & 15, lg = lane >> 4;
    int rbase = blockIdx.x * 128;

    // ---- prefetch: A fragments (both halves), W1 + W2 staging words ----
    short8 xf2[2][4];
    bool act[2];
#pragma unroll
    for (int t2 = 0; t2 < 2; ++t2) {
        int r0 = rbase + t2 * 64 + w * 16;
        act[t2] = (r0 < M);                   // wave-uniform (M % 16 == 0)
        if (act[t2]) {
            const short* Xp = (const short*)AhiS + (r0 + lm) * 128 + lg * 8;
#pragma unroll
            for (int kb = 0; kb < 4; ++kb) xf2[t2][kb] = *(const short8*)(Xp + kb * 32);
        } else {
#pragma unroll
            for (int kb = 0; kb < 4; ++kb) xf2[t2][kb] = (short8){0,0,0,0,0,0,0,0};
        }
    }
    constexpr int W2CH = (NT2 * 16 * 128) / 2048;   // 8 or 3
    short8 w1r[8], w2r[W2CH];
#pragma unroll
    for (int u = 0; u < 8; ++u) w1r[u] = *(const short8*)(W1h + t * 8 + u * 2048);
#pragma unroll
    for (int u = 0; u < W2CH; ++u) w2r[u] = *(const short8*)(W2h + t * 8 + u * 2048);

    // ---- stage W1 ----
#pragma unroll
    for (int u = 0; u < 8; ++u) {
        int i = t * 8 + u * 2048;
        *(short8*)&wbuf[(i >> 7) * 136 + (i & 127)] = w1r[u];
    }
    __syncthreads();

    // ---- GEMM1 (a = W1 frag, b = node frag  ->  D = H^T), pack H in registers ----
    short4v h2[2][8];
#pragma unroll
    for (int t2 = 0; t2 < 2; ++t2) {
        float4v acc1[8];
#pragma unroll
        for (int nt = 0; nt < 8; ++nt) acc1[nt] = (float4v){0.f, 0.f, 0.f, 0.f};
#pragma unroll
        for (int nt = 0; nt < 8; ++nt) {
#pragma unroll
            for (int kb = 0; kb < 4; ++kb) {
                short8 wf = *(const short8*)&wbuf[(nt * 16 + lm) * 136 + kb * 32 + lg * 8];
                acc1[nt] = __builtin_amdgcn_mfma_f32_16x16x32_bf16(wf, xf2[t2][kb], acc1[nt], 0, 0, 0);
            }
        }
#pragma unroll
        for (int nt = 0; nt < 8; ++nt) {
            float4 b1 = *(const float4*)(B1 + nt * 16 + lg * 4);
            float v0 = acc1[nt][0] + b1.x; v0 = v0 > 0.f ? v0 : 0.f;
            float v1 = acc1[nt][1] + b1.y; v1 = v1 > 0.f ? v1 : 0.f;
            float v2 = acc1[nt][2] + b1.z; v2 = v2 > 0.f ? v2 : 0.f;
            float v3 = acc1[nt][3] + b1.w; v3 = v3 > 0.f ? v3 : 0.f;
            h2[t2][nt] = (short4v){(short)f2bf(v0), (short)f2bf(v1),
                                   (short)f2bf(v2), (short)f2bf(v3)};
        }
    }

    __syncthreads();
    // ---- stage W2 (from prefetched registers) ----
#pragma unroll
    for (int u = 0; u < W2CH; ++u) {
        int i = t * 8 + u * 2048;
        *(short8*)&wbuf[(i >> 7) * 136 + (i & 127)] = w2r[u];
    }
    __syncthreads();

    // ---- GEMM2: K=16 MFMAs consume h2 directly (B-operand layout match) ----
    float4v acc2[2][NT2];
#pragma unroll
    for (int t2 = 0; t2 < 2; ++t2)
#pragma unroll
        for (int ot = 0; ot < NT2; ++ot) acc2[t2][ot] = (float4v){0.f, 0.f, 0.f, 0.f};
#pragma unroll
    for (int ot = 0; ot < NT2; ++ot) {
#pragma unroll
        for (int nt = 0; nt < 8; ++nt) {
            short4v wf = *(const short4v*)&wbuf[(ot * 16 + lm) * 136 + nt * 16 + lg * 4];
#pragma unroll
            for (int t2 = 0; t2 < 2; ++t2)
                acc2[t2][ot] = __builtin_amdgcn_mfma_f32_16x16x16bf16_1k(wf, h2[t2][nt],
                                                                         acc2[t2][ot], 0, 0, 0);
        }
    }

    // ---- epilogue: lane owns node (r0+lm), hidden units ot*16+lg*4+{0..3} ----
#pragma unroll
    for (int t2 = 0; t2 < 2; ++t2) {
        if (!act[t2]) continue;
        int row = rbase + t2 * 64 + w * 16 + lm;
        if (!LOGITS) {
#pragma unroll
            for (int ot = 0; ot < NT2; ++ot) {
                float4 b2 = *(const float4*)(B2 + ot * 16 + lg * 4);
                float v0 = acc2[t2][ot][0] + b2.x; v0 = v0 > 0.f ? v0 : 0.f;
                float v1 = acc2[t2][ot][1] + b2.y; v1 = v1 > 0.f ? v1 : 0.f;
                float v2 = acc2[t2][ot][2] + b2.z; v2 = v2 > 0.f ? v2 : 0.f;
                float v3 = acc2[t2][ot][3] + b2.w; v3 = v3 > 0.f ? v3 : 0.f;
                uint2 pk;
                pk.x = ((unsigned int)f2bf(v1) << 16) | f2bf(v0);
                pk.y = ((unsigned int)f2bf(v3) << 16) | f2bf(v2);
                *(uint2*)(HOut + row * 128 + ot * 16 + lg * 4) = pk;
            }
        } else {
            float vv[NT2][4];
#pragma unroll
            for (int ot = 0; ot < NT2; ++ot) {
                int ub = ot * 16 + lg * 4;
                bool valid = ub <= 36;
                float4 b2 = valid ? *(const float4*)(B2 + ub) : (float4){0.f, 0.f, 0.f, 0.f};
                vv[ot][0] = valid ? acc2[t2][ot][0] + b2.x : -1e30f;
                vv[ot][1] = valid ? acc2[t2][ot][1] + b2.y : -1e30f;
                vv[ot][2] = valid ? acc2[t2][ot][2] + b2.z : -1e30f;
                vv[ot][3] = valid ? acc2[t2][ot][3] + b2.w : -1e30f;
            }
            float m = -1e30f;
#pragma unroll
            for (int ot = 0; ot < NT2; ++ot)
#pragma unroll
                for (int r = 0; r < 4; ++r) m = fmaxf(m, vv[ot][r]);
            m = fmaxf(m, __shfl_xor(m, 16, 64));
            m = fmaxf(m, __shfl_xor(m, 32, 64));
            float s = 0.f;
#pragma unroll
            for (int ot = 0; ot < NT2; ++ot)
#pragma unroll
                for (int r = 0; r < 4; ++r)
                    s += (vv[ot][r] > -1e29f) ? expf(vv[ot][r] - m) : 0.f;
            s += __shfl_xor(s, 16, 64);
            s += __shfl_xor(s, 32, 64);
            float ls = m + logf(s);
#pragma unroll
            for (int ot = 0; ot < NT2; ++ot) {
                int ub = ot * 16 + lg * 4;
                if (ub <= 36) {
                    float4 outv = {vv[ot][0] - ls, vv[ot][1] - ls,
                                   vv[ot][2] - ls, vv[ot][3] - ls};
                    *(float4*)(LOut + row * 40 + ub) = outv;
                }
            }
        }
    }
}

// ---------------- launch ----------------
extern "C" void kernel_launch(void* const* d_in, const int* in_sizes, int n_in,
                              void* d_out, int out_size, void* d_ws, size_t ws_size,
                              hipStream_t stream) {
    const float* x    = (const float*)d_in[0];
    const int*   edges = (const int*)d_in[1];
    const float* eps0 = (const float*)d_in[6];
    const float* eps1 = (const float*)d_in[11];
    const float* eps2 = (const float*)d_in[16];
    const float* B1[3] = {(const float*)d_in[3], (const float*)d_in[8], (const float*)d_in[13]};
    const float* B2[3] = {(const float*)d_in[5], (const float*)d_in[10], (const float*)d_in[15]};

    int M  = in_sizes[0] / 128;   // 100000
    int nE = in_sizes[1] / 2;     // 1600000
    const int* e_src = edges;
    const int* e_dst = edges + nE;

    char* ws = (char*)d_ws;
    size_t o = 0;
    auto alloc = [&](size_t bytes) {
        size_t p = o;
        o = (o + bytes + 511) & ~(size_t)511;
        return ws + p;
    };
    int* bucketCnt  = (int*)alloc(512 * 4);
    int* bucketBase = (int*)alloc(513 * 4);
    int* bucketCur  = (int*)alloc(512 * 4);
    int* off  = (int*)alloc((size_t)(M + 1) * 4);
    int* esrc = (int*)alloc((size_t)nE * 4);
    unsigned int* ebuf = (unsigned int*)alloc((size_t)nE * 4);

    Prep pp;
    pp.W[0] = (const float*)d_in[2];  pp.W[1] = (const float*)d_in[4];
    pp.W[2] = (const float*)d_in[7];  pp.W[3] = (const float*)d_in[9];
    pp.W[4] = (const float*)d_in[12]; pp.W[5] = (const float*)d_in[14];
    for (int m = 0; m < 6; ++m) {
        int npad = (m == 5) ? 48 : 128;
        pp.hi[m] = (unsigned short*)alloc((size_t)npad * 128 * 2);
    }
    unsigned short* xb  = (unsigned short*)alloc((size_t)M * 128 * 2);
    unsigned short* Ahi = (unsigned short*)alloc((size_t)M * 128 * 2);
    unsigned short* Hb  = (unsigned short*)alloc((size_t)M * 128 * 2);
    pp.xin = (const float4*)x;
    pp.xout = (uint2*)xb;
    pp.n4 = M * 32;
    pp.bucketCnt = bucketCnt;
    (void)ws_size; (void)n_in; (void)out_size;

    int nChunk = (nE + 4095) / 4096;
    int nBk = (M + 255) / 256;
    k_prep<<<344 + (pp.n4 + 255) / 256, 256, 0, stream>>>(pp);   // also zeroes bucketCnt
    bs_count<<<nChunk, 256, 0, stream>>>(e_dst, nE, bucketCnt);
    bs_scan<<<1, 512, 0, stream>>>(bucketCnt, bucketBase, bucketCur, off, M, nE);
    bs_scatter<<<nChunk, 512, 0, stream>>>(e_src, e_dst, nE, bucketCur, ebuf);
    bs_build<<<nBk, 512, 0, stream>>>(ebuf, bucketBase, off, esrc, M);

    // aggr split into two half-grids (diagnostic: expose k_mlp/CSR in top-5)
    int h0 = ((M / 2) + 15) & ~15;          // 50000 (multiple of 16)
    int gA0 = (h0 + 15) / 16;
    int gA1 = (M - h0 + 15) / 16;
    int gG = (M + 127) / 128;               // 782

    // layer 0
    k_aggr<<<gA0, 256, 0, stream>>>((const uint4*)xb, off, esrc, eps0, (uint4*)Ahi, 0, h0);
    k_aggr<<<gA1, 256, 0, stream>>>((const uint4*)xb, off, esrc, eps0, (uint4*)Ahi, h0, M);
    k_mlp<8, false><<<gG, 256, 0, stream>>>(Ahi, pp.hi[0], B1[0],
                                            pp.hi[1], B2[0], Hb, nullptr, M);
    // layer 1
    k_aggr<<<gA0, 256, 0, stream>>>((const uint4*)Hb, off, esrc, eps1, (uint4*)Ahi, 0, h0);
    k_aggr<<<gA1, 256, 0, stream>>>((const uint4*)Hb, off, esrc, eps1, (uint4*)Ahi, h0, M);
    k_mlp<8, false><<<gG, 256, 0, stream>>>(Ahi, pp.hi[2], B1[1],
                                            pp.hi[3], B2[1], Hb, nullptr, M);
    // layer 2 (log_softmax fused)
    k_aggr<<<gA0, 256, 0, stream>>>((const uint4*)Hb, off, esrc, eps2, (uint4*)Ahi, 0, h0);
    k_aggr<<<gA1, 256, 0, stream>>>((const uint4*)Hb, off, esrc, eps2, (uint4*)Ahi, h0, M);
    k_mlp<3, true><<<gG, 256, 0, stream>>>(Ahi, pp.hi[4], B1[2],
                                           pp.hi[5], B2[2], nullptr,
                                           (float*)d_out, M);
}

// Round 10
// 402.164 us; speedup vs baseline: 1.0341x; 1.0341x over previous
//
#include <hip/hip_runtime.h>
#include <stdint.h>

typedef __attribute__((ext_vector_type(8))) short short8;
typedef __attribute__((ext_vector_type(4))) short short4v;
typedef __attribute__((ext_vector_type(4))) float float4v;

__device__ __forceinline__ float bf2f(unsigned short s) {
    union { unsigned int u; float f; } c; c.u = ((unsigned int)s) << 16; return c.f;
}
__device__ __forceinline__ unsigned short f2bf(float f) {
    union { float f; unsigned int u; } c; c.f = f;
    unsigned int x = c.u;
    unsigned int r = x + 0x7fffu + ((x >> 16) & 1u);   // RNE
    return (unsigned short)(r >> 16);
}
__device__ __forceinline__ void unpack2(unsigned int u, float& lo, float& hi) {
    union { unsigned int uu; float ff; } a, b;
    a.uu = u << 16;          // low bf16
    b.uu = u & 0xffff0000u;  // high bf16
    lo = a.ff; hi = b.ff;
}

// ================= CSR build via bucket sort (bucket = dst>>8) =================
__global__ __launch_bounds__(256) void bs_count(const int* __restrict__ dst, int nE,
                                                int* __restrict__ bucketCnt) {
    __shared__ int c[512];
    int t = threadIdx.x;
    for (int i = t; i < 512; i += 256) c[i] = 0;
    __syncthreads();
    int base = blockIdx.x * 4096;
    for (int i = t; i < 4096; i += 256) {
        int e = base + i;
        if (e < nE) atomicAdd(&c[dst[e] >> 8], 1);
    }
    __syncthreads();
    for (int i = t; i < 512; i += 256)
        if (c[i]) atomicAdd(&bucketCnt[i], c[i]);
}

__global__ __launch_bounds__(512) void bs_scan(const int* __restrict__ bucketCnt,
                                               int* __restrict__ bucketBase,
                                               int* __restrict__ bucketCur,
                                               int* __restrict__ off, int M, int nE) {
    __shared__ int s[512];
    int t = threadIdx.x;
    int v = bucketCnt[t];
    s[t] = v;
    __syncthreads();
    for (int o = 1; o < 512; o <<= 1) {
        int x = (t >= o) ? s[t - o] : 0;
        __syncthreads();
        s[t] += x;
        __syncthreads();
    }
    bucketBase[t] = s[t] - v;
    bucketCur[t] = s[t] - v;
    if (t == 511) bucketBase[512] = s[511];
    if (t == 0) off[M] = nE;
}

// packed entry: src (bits 0..16) | (dst&255)<<17
__global__ __launch_bounds__(512) void bs_scatter(const int* __restrict__ src,
                                                  const int* __restrict__ dst, int nE,
                                                  int* __restrict__ bucketCur,
                                                  unsigned int* __restrict__ ebuf) {
    __shared__ int cnt[512];
    __shared__ int excl[512];
    __shared__ int chunk[512];
    __shared__ unsigned int buf[4096];
    __shared__ unsigned short bkt[4096];
    int t = threadIdx.x;
    cnt[t] = 0;
    __syncthreads();
    int base = blockIdx.x * 4096;
    int n = nE - base; if (n > 4096) n = 4096;
    unsigned int pk[8]; int bk[8]; int rk[8];
#pragma unroll
    for (int u = 0; u < 8; ++u) {
        int i = t + u * 512;
        if (i < n) {
            int e = base + i;
            int d = dst[e];
            int b = d >> 8;
            bk[u] = b;
            pk[u] = (unsigned int)src[e] | ((unsigned int)(d & 255) << 17);
            rk[u] = atomicAdd(&cnt[b], 1);
        } else bk[u] = -1;
    }
    __syncthreads();
    excl[t] = cnt[t];
    __syncthreads();
    for (int o = 1; o < 512; o <<= 1) {
        int x = (t >= o) ? excl[t - o] : 0;
        __syncthreads();
        excl[t] += x;
        __syncthreads();
    }
    int ex = excl[t] - cnt[t];
    __syncthreads();
    excl[t] = ex;
    if (cnt[t]) chunk[t] = atomicAdd(&bucketCur[t], cnt[t]);
    __syncthreads();
#pragma unroll
    for (int u = 0; u < 8; ++u) {
        if (bk[u] >= 0) {
            int lp = excl[bk[u]] + rk[u];
            buf[lp] = pk[u];
            bkt[lp] = (unsigned short)bk[u];
        }
    }
    __syncthreads();
    for (int i = t; i < n; i += 512) {
        int b = bkt[i];
        ebuf[chunk[b] + (i - excl[b])] = buf[i];
    }
}

__global__ __launch_bounds__(512) void bs_build(const unsigned int* __restrict__ ebuf,
                                                const int* __restrict__ bucketBase,
                                                int* __restrict__ off,
                                                int* __restrict__ esrc, int M) {
    __shared__ int cnt[256];
    __shared__ int excl[256];
    __shared__ int obuf[5120];
    int t = threadIdx.x, b = blockIdx.x;
    int base = bucketBase[b];
    int n = bucketBase[b + 1] - base;
    if (t < 256) cnt[t] = 0;
    __syncthreads();
    unsigned int pk[10]; int dl[10]; int rk[10];
#pragma unroll
    for (int u = 0; u < 10; ++u) {
        int i = t + u * 512;
        if (i < n) {
            unsigned int p = ebuf[base + i];
            pk[u] = p;
            int d = (p >> 17) & 255;
            dl[u] = d;
            rk[u] = atomicAdd(&cnt[d], 1);
        } else dl[u] = -1;
    }
    __syncthreads();
    if (t < 256) excl[t] = cnt[t];
    __syncthreads();
    for (int o = 1; o < 256; o <<= 1) {
        int x = (t < 256 && t >= o) ? excl[t - o] : 0;
        __syncthreads();
        if (t < 256) excl[t] += x;
        __syncthreads();
    }
    if (t < 256) {
        int ex = excl[t] - cnt[t];
        int node = b * 256 + t;
        if (node < M) off[node] = base + ex;
        excl[t] = ex;
    }
    __syncthreads();
#pragma unroll
    for (int u = 0; u < 10; ++u) {
        if (dl[u] >= 0) {
            int lp = excl[dl[u]] + rk[u];
            if (lp < 5120) obuf[lp] = (int)(pk[u] & 0x1FFFF);
        }
    }
    __syncthreads();
    for (int i = t; i < n; i += 512) esrc[base + i] = obuf[i];
}

// ==== combined prep: zero bucketCnt; weights fp32 W[k][n] -> bf16 [n][k]; x -> bf16 ====
struct Prep {
    const float* W[6];
    unsigned short* hi[6];
    const float4* xin;
    uint2* xout;
    int n4;
    int* bucketCnt;
};

__global__ __launch_bounds__(256) void k_prep(Prep p) {
    int b = blockIdx.x;
    if (b == 0) {             // zero bucketCnt (bs_count dispatched after this kernel)
        p.bucketCnt[threadIdx.x] = 0;
        p.bucketCnt[threadIdx.x + 256] = 0;
    }
    if (b < 344) {
        int mat = b >> 6;     // mats 0..4: 64 blocks each; mat 5: blocks 320..343
        int rel = b - mat * 64;
        int NPAD = (mat == 5) ? 48 : 128;
        int N = (mat == 5) ? 40 : 128;
        int idx = rel * 256 + threadIdx.x;
        if (idx >= NPAD * 128) return;
        int n = idx >> 7, k = idx & 127;
        float w = (n < N) ? p.W[mat][k * N + n] : 0.f;
        p.hi[mat][idx] = f2bf(w);
    } else {
        int i = (b - 344) * 256 + threadIdx.x;
        if (i >= p.n4) return;
        float4 v = p.xin[i];
        uint2 o;
        o.x = ((unsigned int)f2bf(v.y) << 16) | f2bf(v.x);
        o.y = ((unsigned int)f2bf(v.w) << 16) | f2bf(v.z);
        p.xout[i] = o;
    }
}

// ======= aggregation: a = (1+eps)*h + sum_{j->i} h_j (h bf16) ; emit bf16 =======
// One node per 16-lane quarter. Software-pipelined: next batch's esrc indices are
// loaded while current batch's row gathers are in flight, breaking the serial
// index->row dependency chain per batch.
__device__ __forceinline__ void acc8(uint4 v, float* s) {
    float a, b;
    unpack2(v.x, a, b); s[0] += a; s[1] += b;
    unpack2(v.y, a, b); s[2] += a; s[3] += b;
    unpack2(v.z, a, b); s[4] += a; s[5] += b;
    unpack2(v.w, a, b); s[6] += a; s[7] += b;
}

__global__ __launch_bounds__(256) void k_aggr(const uint4* __restrict__ Hin,
                                              const int* __restrict__ off,
                                              const int* __restrict__ esrc,
                                              const float* __restrict__ epsp,
                                              uint4* __restrict__ Ahi, int M) {
    int w = threadIdx.x >> 6, lane = threadIdx.x & 63;
    int li = lane & 15, q = lane >> 4;
    int node = blockIdx.x * 16 + w * 4 + q;
    if (node >= M) return;
    float ep = 1.0f + epsp[0];
    uint4 ow = Hin[node * 16 + li];
    float s[8] = {0.f, 0.f, 0.f, 0.f, 0.f, 0.f, 0.f, 0.f};
    int i = off[node], e = off[node + 1];
    int idx[8];
    if (i + 8 <= e) {
#pragma unroll
        for (int j = 0; j < 8; ++j) idx[j] = esrc[i + j];
    }
    while (i + 8 <= e) {
        // issue row gathers for current indices
        uint4 v[8];
#pragma unroll
        for (int j = 0; j < 8; ++j) v[j] = Hin[idx[j] * 16 + li];
        int inext = i + 8;
        // prefetch next batch's indices while rows are in flight
        if (inext + 8 <= e) {
#pragma unroll
            for (int j = 0; j < 8; ++j) idx[j] = esrc[inext + j];
        }
#pragma unroll
        for (int j = 0; j < 8; ++j) acc8(v[j], s);
        i = inext;
    }
    // tail: one predicated batch (clamped duplicate loads are L1 hits, masked to 0)
    if (i < e) {
        int last = e - 1;
        uint4 v[8];
#pragma unroll
        for (int j = 0; j < 8; ++j) {
            int k = i + j;
            int cl = k < last ? k : last;
            v[j] = Hin[esrc[cl] * 16 + li];
        }
#pragma unroll
        for (int j = 0; j < 8; ++j) {
            bool ok = (i + j) < e;
            uint4 u;
            u.x = ok ? v[j].x : 0u;
            u.y = ok ? v[j].y : 0u;
            u.z = ok ? v[j].z : 0u;
            u.w = ok ? v[j].w : 0u;
            acc8(u, s);
        }
    }
    float o[8];
    unpack2(ow.x, o[0], o[1]);
    unpack2(ow.y, o[2], o[3]);
    unpack2(ow.z, o[4], o[5]);
    unpack2(ow.w, o[6], o[7]);
#pragma unroll
    for (int k = 0; k < 8; ++k) s[k] = ep * o[k] + s[k];
    uint4 r;
    r.x = ((unsigned int)f2bf(s[1]) << 16) | f2bf(s[0]);
    r.y = ((unsigned int)f2bf(s[3]) << 16) | f2bf(s[2]);
    r.z = ((unsigned int)f2bf(s[5]) << 16) | f2bf(s[4]);
    r.w = ((unsigned int)f2bf(s[7]) << 16) | f2bf(s[6]);
    Ahi[node * 16 + li] = r;
}

// ============ fused 2-layer MLP, transpose-free, fully software-pipelined ============
template <int NT2, bool LOGITS>
__global__ __launch_bounds__(256, 2) void k_mlp(const unsigned short* __restrict__ AhiS,
                                                const unsigned short* __restrict__ W1h,
                                                const float* __restrict__ B1,
                                                const unsigned short* __restrict__ W2h,
                                                const float* __restrict__ B2,
                                                unsigned short* __restrict__ HOut,
                                                float* __restrict__ LOut, int M) {
    __shared__ short wbuf[128 * 136];     // 272 B row stride
    int t = threadIdx.x, w = t >> 6, lane = t & 63;
    int lm = lane & 15, lg = lane >> 4;
    int rbase = blockIdx.x * 128;

    // ---- prefetch: A fragments (both halves), W1 + W2 staging words ----
    short8 xf2[2][4];
    bool act[2];
#pragma unroll
    for (int t2 = 0; t2 < 2; ++t2) {
        int r0 = rbase + t2 * 64 + w * 16;
        act[t2] = (r0 < M);                   // wave-uniform (M % 16 == 0)
        if (act[t2]) {
            const short* Xp = (const short*)AhiS + (r0 + lm) * 128 + lg * 8;
#pragma unroll
            for (int kb = 0; kb < 4; ++kb) xf2[t2][kb] = *(const short8*)(Xp + kb * 32);
        } else {
#pragma unroll
            for (int kb = 0; kb < 4; ++kb) xf2[t2][kb] = (short8){0,0,0,0,0,0,0,0};
        }
    }
    constexpr int W2CH = (NT2 * 16 * 128) / 2048;   // 8 or 3
    short8 w1r[8], w2r[W2CH];
#pragma unroll
    for (int u = 0; u < 8; ++u) w1r[u] = *(const short8*)(W1h + t * 8 + u * 2048);
#pragma unroll
    for (int u = 0; u < W2CH; ++u) w2r[u] = *(const short8*)(W2h + t * 8 + u * 2048);

    // ---- stage W1 ----
#pragma unroll
    for (int u = 0; u < 8; ++u) {
        int i = t * 8 + u * 2048;
        *(short8*)&wbuf[(i >> 7) * 136 + (i & 127)] = w1r[u];
    }
    __syncthreads();

    // ---- GEMM1 (a = W1 frag, b = node frag  ->  D = H^T), pack H in registers ----
    short4v h2[2][8];
#pragma unroll
    for (int t2 = 0; t2 < 2; ++t2) {
        float4v acc1[8];
#pragma unroll
        for (int nt = 0; nt < 8; ++nt) acc1[nt] = (float4v){0.f, 0.f, 0.f, 0.f};
#pragma unroll
        for (int nt = 0; nt < 8; ++nt) {
#pragma unroll
            for (int kb = 0; kb < 4; ++kb) {
                short8 wf = *(const short8*)&wbuf[(nt * 16 + lm) * 136 + kb * 32 + lg * 8];
                acc1[nt] = __builtin_amdgcn_mfma_f32_16x16x32_bf16(wf, xf2[t2][kb], acc1[nt], 0, 0, 0);
            }
        }
#pragma unroll
        for (int nt = 0; nt < 8; ++nt) {
            float4 b1 = *(const float4*)(B1 + nt * 16 + lg * 4);
            float v0 = acc1[nt][0] + b1.x; v0 = v0 > 0.f ? v0 : 0.f;
            float v1 = acc1[nt][1] + b1.y; v1 = v1 > 0.f ? v1 : 0.f;
            float v2 = acc1[nt][2] + b1.z; v2 = v2 > 0.f ? v2 : 0.f;
            float v3 = acc1[nt][3] + b1.w; v3 = v3 > 0.f ? v3 : 0.f;
            h2[t2][nt] = (short4v){(short)f2bf(v0), (short)f2bf(v1),
                                   (short)f2bf(v2), (short)f2bf(v3)};
        }
    }

    __syncthreads();
    // ---- stage W2 (from prefetched registers) ----
#pragma unroll
    for (int u = 0; u < W2CH; ++u) {
        int i = t * 8 + u * 2048;
        *(short8*)&wbuf[(i >> 7) * 136 + (i & 127)] = w2r[u];
    }
    __syncthreads();

    // ---- GEMM2: K=16 MFMAs consume h2 directly (B-operand layout match) ----
    float4v acc2[2][NT2];
#pragma unroll
    for (int t2 = 0; t2 < 2; ++t2)
#pragma unroll
        for (int ot = 0; ot < NT2; ++ot) acc2[t2][ot] = (float4v){0.f, 0.f, 0.f, 0.f};
#pragma unroll
    for (int ot = 0; ot < NT2; ++ot) {
#pragma unroll
        for (int nt = 0; nt < 8; ++nt) {
            short4v wf = *(const short4v*)&wbuf[(ot * 16 + lm) * 136 + nt * 16 + lg * 4];
#pragma unroll
            for (int t2 = 0; t2 < 2; ++t2)
                acc2[t2][ot] = __builtin_amdgcn_mfma_f32_16x16x16bf16_1k(wf, h2[t2][nt],
                                                                         acc2[t2][ot], 0, 0, 0);
        }
    }

    // ---- epilogue: lane owns node (r0+lm), hidden units ot*16+lg*4+{0..3} ----
#pragma unroll
    for (int t2 = 0; t2 < 2; ++t2) {
        if (!act[t2]) continue;
        int row = rbase + t2 * 64 + w * 16 + lm;
        if (!LOGITS) {
#pragma unroll
            for (int ot = 0; ot < NT2; ++ot) {
                float4 b2 = *(const float4*)(B2 + ot * 16 + lg * 4);
                float v0 = acc2[t2][ot][0] + b2.x; v0 = v0 > 0.f ? v0 : 0.f;
                float v1 = acc2[t2][ot][1] + b2.y; v1 = v1 > 0.f ? v1 : 0.f;
                float v2 = acc2[t2][ot][2] + b2.z; v2 = v2 > 0.f ? v2 : 0.f;
                float v3 = acc2[t2][ot][3] + b2.w; v3 = v3 > 0.f ? v3 : 0.f;
                uint2 pk;
                pk.x = ((unsigned int)f2bf(v1) << 16) | f2bf(v0);
                pk.y = ((unsigned int)f2bf(v3) << 16) | f2bf(v2);
                *(uint2*)(HOut + row * 128 + ot * 16 + lg * 4) = pk;
            }
        } else {
            float vv[NT2][4];
#pragma unroll
            for (int ot = 0; ot < NT2; ++ot) {
                int ub = ot * 16 + lg * 4;
                bool valid = ub <= 36;
                float4 b2 = valid ? *(const float4*)(B2 + ub) : (float4){0.f, 0.f, 0.f, 0.f};
                vv[ot][0] = valid ? acc2[t2][ot][0] + b2.x : -1e30f;
                vv[ot][1] = valid ? acc2[t2][ot][1] + b2.y : -1e30f;
                vv[ot][2] = valid ? acc2[t2][ot][2] + b2.z : -1e30f;
                vv[ot][3] = valid ? acc2[t2][ot][3] + b2.w : -1e30f;
            }
            float m = -1e30f;
#pragma unroll
            for (int ot = 0; ot < NT2; ++ot)
#pragma unroll
                for (int r = 0; r < 4; ++r) m = fmaxf(m, vv[ot][r]);
            m = fmaxf(m, __shfl_xor(m, 16, 64));
            m = fmaxf(m, __shfl_xor(m, 32, 64));
            float s = 0.f;
#pragma unroll
            for (int ot = 0; ot < NT2; ++ot)
#pragma unroll
                for (int r = 0; r < 4; ++r)
                    s += (vv[ot][r] > -1e29f) ? expf(vv[ot][r] - m) : 0.f;
            s += __shfl_xor(s, 16, 64);
            s += __shfl_xor(s, 32, 64);
            float ls = m + logf(s);
#pragma unroll
            for (int ot = 0; ot < NT2; ++ot) {
                int ub = ot * 16 + lg * 4;
                if (ub <= 36) {
                    float4 outv = {vv[ot][0] - ls, vv[ot][1] - ls,
                                   vv[ot][2] - ls, vv[ot][3] - ls};
                    *(float4*)(LOut + row * 40 + ub) = outv;
                }
            }
        }
    }
}

// ---------------- launch ----------------
extern "C" void kernel_launch(void* const* d_in, const int* in_sizes, int n_in,
                              void* d_out, int out_size, void* d_ws, size_t ws_size,
                              hipStream_t stream) {
    const float* x    = (const float*)d_in[0];
    const int*   edges = (const int*)d_in[1];
    const float* eps0 = (const float*)d_in[6];
    const float* eps1 = (const float*)d_in[11];
    const float* eps2 = (const float*)d_in[16];
    const float* B1[3] = {(const float*)d_in[3], (const float*)d_in[8], (const float*)d_in[13]};
    const float* B2[3] = {(const float*)d_in[5], (const float*)d_in[10], (const float*)d_in[15]};

    int M  = in_sizes[0] / 128;   // 100000
    int nE = in_sizes[1] / 2;     // 1600000
    const int* e_src = edges;
    const int* e_dst = edges + nE;

    char* ws = (char*)d_ws;
    size_t o = 0;
    auto alloc = [&](size_t bytes) {
        size_t p = o;
        o = (o + bytes + 511) & ~(size_t)511;
        return ws + p;
    };
    int* bucketCnt  = (int*)alloc(512 * 4);
    int* bucketBase = (int*)alloc(513 * 4);
    int* bucketCur  = (int*)alloc(512 * 4);
    int* off  = (int*)alloc((size_t)(M + 1) * 4);
    int* esrc = (int*)alloc((size_t)nE * 4);
    unsigned int* ebuf = (unsigned int*)alloc((size_t)nE * 4);

    Prep pp;
    pp.W[0] = (const float*)d_in[2];  pp.W[1] = (const float*)d_in[4];
    pp.W[2] = (const float*)d_in[7];  pp.W[3] = (const float*)d_in[9];
    pp.W[4] = (const float*)d_in[12]; pp.W[5] = (const float*)d_in[14];
    for (int m = 0; m < 6; ++m) {
        int npad = (m == 5) ? 48 : 128;
        pp.hi[m] = (unsigned short*)alloc((size_t)npad * 128 * 2);
    }
    unsigned short* xb  = (unsigned short*)alloc((size_t)M * 128 * 2);
    unsigned short* Ahi = (unsigned short*)alloc((size_t)M * 128 * 2);
    unsigned short* Hb  = (unsigned short*)alloc((size_t)M * 128 * 2);
    pp.xin = (const float4*)x;
    pp.xout = (uint2*)xb;
    pp.n4 = M * 32;
    pp.bucketCnt = bucketCnt;
    (void)ws_size; (void)n_in; (void)out_size;

    int nChunk = (nE + 4095) / 4096;
    int nBk = (M + 255) / 256;
    k_prep<<<344 + (pp.n4 + 255) / 256, 256, 0, stream>>>(pp);   // also zeroes bucketCnt
    bs_count<<<nChunk, 256, 0, stream>>>(e_dst, nE, bucketCnt);
    bs_scan<<<1, 512, 0, stream>>>(bucketCnt, bucketBase, bucketCur, off, M, nE);
    bs_scatter<<<nChunk, 512, 0, stream>>>(e_src, e_dst, nE, bucketCur, ebuf);
    bs_build<<<nBk, 512, 0, stream>>>(ebuf, bucketBase, off, esrc, M);

    int gA = (M + 15) / 16;      // 6250
    int gG = (M + 127) / 128;    // 782

    // layer 0
    k_aggr<<<gA, 256, 0, stream>>>((const uint4*)xb, off, esrc, eps0, (uint4*)Ahi, M);
    k_mlp<8, false><<<gG, 256, 0, stream>>>(Ahi, pp.hi[0], B1[0],
                                            pp.hi[1], B2[0], Hb, nullptr, M);
    // layer 1
    k_aggr<<<gA, 256, 0, stream>>>((const uint4*)Hb, off, esrc, eps1, (uint4*)Ahi, M);
    k_mlp<8, false><<<gG, 256, 0, stream>>>(Ahi, pp.hi[2], B1[1],
                                            pp.hi[3], B2[1], Hb, nullptr, M);
    // layer 2 (log_softmax fused)
    k_aggr<<<gA, 256, 0, stream>>>((const uint4*)Hb, off, esrc, eps2, (uint4*)Ahi, M);
    k_mlp<3, true><<<gG, 256, 0, stream>>>(Ahi, pp.hi[4], B1[2],
                                           pp.hi[5], B2[2], nullptr,
                                           (float*)d_out, M);
}